// Round 7
// baseline (291.208 us; speedup 1.0000x reference)
//
#include <hip/hip_runtime.h>
#include <hip/hip_bf16.h>

#define B_SZ 8192
#define D_SZ 256
// rows pre-scaled by sqrt(log2(e)/T): exp2(acc) == exp(sim/T)
#define PRESCALE 4.539816004686735f

typedef __attribute__((ext_vector_type(4))) float f32x4;
typedef __attribute__((ext_vector_type(8))) short s16x8;

// ---- async global->LDS, 16B per lane (wave-uniform LDS base + lane*16) ----
__device__ __forceinline__ void async_copy16(const void* g, void* l) {
    __builtin_amdgcn_global_load_lds(
        (const __attribute__((address_space(1))) unsigned int*)g,
        (__attribute__((address_space(3))) unsigned int*)l,
        16, 0, 0);
}

// ---------------- L2-normalize rows, scale, cast to bf16 (+ zero sums) -----
__global__ __launch_bounds__(256) void norm_kernel(const float* __restrict__ emb,
                                                   ushort* __restrict__ nbf,
                                                   float* __restrict__ sums) {
    if (blockIdx.x < 64) sums[blockIdx.x * 256 + threadIdx.x] = 0.0f;

    int wave = threadIdx.x >> 6, lane = threadIdx.x & 63;
    int row  = blockIdx.x * 4 + wave;
    const float4 v = ((const float4*)(emb + (size_t)row * D_SZ))[lane];
    float ss = v.x * v.x + v.y * v.y + v.z * v.z + v.w * v.w;
    #pragma unroll
    for (int m = 1; m < 64; m <<= 1) ss += __shfl_xor(ss, m, 64);
    float s = PRESCALE / fmaxf(sqrtf(ss), 1e-12f);
    __hip_bfloat16 b0 = __float2bfloat16(v.x * s);
    __hip_bfloat16 b1 = __float2bfloat16(v.y * s);
    __hip_bfloat16 b2 = __float2bfloat16(v.z * s);
    __hip_bfloat16 b3 = __float2bfloat16(v.w * s);
    ushort4 o;
    o.x = *(ushort*)&b0; o.y = *(ushort*)&b1; o.z = *(ushort*)&b2; o.w = *(ushort*)&b3;
    ((ushort4*)(nbf + (size_t)row * D_SZ))[lane] = o;
}

// ---------------- fused sim tile: upper triangle, LDS-staged matmul --------
// 128x128 tile, 512 threads = 8 waves (2x4: wy rows-64, wx cols-32).
// BK=128 -> only 2 K-stages (4 barriers/block). LDS 64KB -> 2 blocks/CU.
// 16-chunk XOR swizzle: slot c of row r holds global chunk c^(r&15);
// fragment reads use slot C^(lane&15) -> 2-way banks (free).
// launch_bounds(512,4): VGPR cap 128 >= ~90 needed -> NO SPILL (r6 lesson).
__global__ __launch_bounds__(512, 4) void sim_kernel(const ushort* __restrict__ N,
                                                     const int* __restrict__ ids,
                                                     float* __restrict__ all_sum,
                                                     float* __restrict__ pos_sum) {
    __shared__ ushort sA[128 * 128];  // reused: rowAll partials [128][18] f32
    __shared__ ushort sB[128 * 128];  // reused: rowPos partials [128][18] f32
    __shared__ int   sIdR[128], sIdC[128];

    const int t    = threadIdx.x;
    const int wave = t >> 6, lane = t & 63;
    const int wy   = wave >> 2, wx = wave & 3;

    // decode upper-triangular tile pair: tb = bj*(bj+1)/2 + bi, bi <= bj
    int tb = blockIdx.x;
    int bj = (int)((sqrtf(8.0f * tb + 1.0f) - 1.0f) * 0.5f);
    while ((bj + 1) * (bj + 2) / 2 <= tb) ++bj;
    while (bj * (bj + 1) / 2 > tb) --bj;
    const int bi   = tb - bj * (bj + 1) / 2;
    const int i0   = bi * 128;
    const int j0   = bj * 128;
    const bool diag = (bi == bj);

    if (t < 128)      sIdR[t] = ids[i0 + t];
    else if (t < 256) sIdC[t - 128] = ids[j0 + (t - 128)];
    // (first K-loop barrier orders these before epilogue use)

    f32x4 acc[4][2];
    #pragma unroll
    for (int mi = 0; mi < 4; ++mi)
        #pragma unroll
        for (int ni = 0; ni < 2; ++ni)
            acc[mi][ni] = (f32x4){0.f, 0.f, 0.f, 0.f};

    const int r4 = lane >> 4;        // 0..3 sub-row within 4-row chunk
    const int cs = lane & 15;        // dest slot 0..15

    for (int kk = 0; kk < 2; ++kk) {
        const int k0 = kk * 128;
        // wave stages 16 rows of A and 16 rows of B; 4 instrs each (4 rows/instr)
        const ushort* gA = N + (size_t)(i0 + wave * 16) * D_SZ + k0;
        const ushort* gB = N + (size_t)(j0 + wave * 16) * D_SZ + k0;
        #pragma unroll
        for (int q = 0; q < 4; ++q) {
            const int rl  = q * 4 + r4;             // row 0..15 within wave's 16
            const int src = (cs ^ (rl & 15)) * 8;   // swizzled source chunk
            async_copy16(gA + (size_t)rl * D_SZ + src, &sA[(wave * 16 + q * 4) * 128]);
            async_copy16(gB + (size_t)rl * D_SZ + src, &sB[(wave * 16 + q * 4) * 128]);
        }
        __syncthreads();

        #pragma unroll
        for (int ks = 0; ks < 4; ++ks) {
            const int C = ks * 4 + (lane >> 4);       // k-chunk 0..15
            const int slot = (C ^ (lane & 15)) * 8;   // un-swizzle
            s16x8 af[4], bf[2];
            #pragma unroll
            for (int mi = 0; mi < 4; ++mi)
                af[mi] = *(const s16x8*)&sA[(wy * 64 + mi * 16 + (lane & 15)) * 128 + slot];
            #pragma unroll
            for (int ni = 0; ni < 2; ++ni)
                bf[ni] = *(const s16x8*)&sB[(wx * 32 + ni * 16 + (lane & 15)) * 128 + slot];
            #pragma unroll
            for (int mi = 0; mi < 4; ++mi)
                #pragma unroll
                for (int ni = 0; ni < 2; ++ni)
                    acc[mi][ni] = __builtin_amdgcn_mfma_f32_16x16x32_bf16(
                        af[mi], bf[ni], acc[mi][ni], 0, 0, 0);
        }
        __syncthreads();   // also guarantees sA/sB free for epilogue reuse
    }

    // ---- epilogue.  C/D map: col=lane&15, row=(lane>>4)*4+reg ----
    float* rowAllPart = (float*)sA;   // [128][18]; stride 18 -> cheap banks
    float* rowPosPart = (float*)sB;

    for (int z = t; z < 128 * 18; z += 512) {
        rowAllPart[z] = 0.0f;
        rowPosPart[z] = 0.0f;
    }
    __syncthreads();

    const int myc = lane & 15;
    float cAll[2] = {0.f, 0.f};
    float cPos[2] = {0.f, 0.f};

    #pragma unroll
    for (int mi = 0; mi < 4; ++mi) {
        float rAll[4] = {0.f, 0.f, 0.f, 0.f};
        float rPos[4] = {0.f, 0.f, 0.f, 0.f};
        const int rbase = wy * 64 + mi * 16 + (lane >> 4) * 4;
        const int4 idr  = *(const int4*)&sIdR[rbase];
        #pragma unroll
        for (int ni = 0; ni < 2; ++ni) {
            const int cloc = wx * 32 + ni * 16 + myc;
            const int idc  = sIdC[cloc];
            #pragma unroll
            for (int rg = 0; rg < 4; ++rg) {
                const int lr = rbase + rg;
                float e = __builtin_amdgcn_exp2f(acc[mi][ni][rg]);
                if (diag && lr == cloc) e = 0.0f;        // diagonal element
                rAll[rg] += e; cAll[ni] += e;
                const int idrv = (rg == 0) ? idr.x : (rg == 1) ? idr.y
                               : (rg == 2) ? idr.z : idr.w;
                if (idrv == idc) { rPos[rg] += e; cPos[ni] += e; }
            }
        }
        #pragma unroll
        for (int rg = 0; rg < 4; ++rg) {
            atomicAdd(&rowAllPart[(rbase + rg) * 18 + myc], rAll[rg]);
            atomicAdd(&rowPosPart[(rbase + rg) * 18 + myc], rPos[rg]);
        }
    }

    // column sums -> rows j (off-diagonal tiles only; symmetry)
    if (!diag) {
        #pragma unroll
        for (int ni = 0; ni < 2; ++ni) {
            cAll[ni] += __shfl_xor(cAll[ni], 16, 64);
            cAll[ni] += __shfl_xor(cAll[ni], 32, 64);
            cPos[ni] += __shfl_xor(cPos[ni], 16, 64);
            cPos[ni] += __shfl_xor(cPos[ni], 32, 64);
        }
        if (lane < 16) {
            #pragma unroll
            for (int ni = 0; ni < 2; ++ni) {
                const int gc = j0 + wx * 32 + ni * 16 + lane;
                atomicAdd(&all_sum[gc], cAll[ni]);
                atomicAdd(&pos_sum[gc], cPos[ni]);
            }
        }
    }

    __syncthreads();
    // row partial reduce: thread t<256 -> (row = t&127, array = t>>7)
    if (t < 256) {
        const int row = t & 127;
        const float* src = (t >= 128) ? rowPosPart : rowAllPart;
        float s = 0.0f;
        #pragma unroll
        for (int k = 0; k < 16; ++k) s += src[row * 18 + k];
        float* dst = (t >= 128) ? pos_sum : all_sum;
        atomicAdd(&dst[i0 + row], s);
    }
}

// ---------------- final scalar reduce ----------------
__global__ __launch_bounds__(256) void loss_kernel(const float* __restrict__ all_sum,
                                                   const float* __restrict__ pos_sum,
                                                   float* __restrict__ out) {
    float loss = 0.0f, cnt = 0.0f;
    for (int i = threadIdx.x; i < B_SZ; i += 256) {
        float p = pos_sum[i], a = all_sum[i];
        if (p > 0.0f) { loss += logf(a) - logf(p); cnt += 1.0f; }
    }
    #pragma unroll
    for (int m = 1; m < 64; m <<= 1) {
        loss += __shfl_xor(loss, m, 64);
        cnt  += __shfl_xor(cnt, m, 64);
    }
    __shared__ float sl[4], sc[4];
    int wave = threadIdx.x >> 6, lane = threadIdx.x & 63;
    if (lane == 0) { sl[wave] = loss; sc[wave] = cnt; }
    __syncthreads();
    if (threadIdx.x == 0) {
        float L = sl[0] + sl[1] + sl[2] + sl[3];
        float C = sc[0] + sc[1] + sc[2] + sc[3];
        out[0] = L / fmaxf(C, 1.0f);
    }
}

extern "C" void kernel_launch(void* const* d_in, const int* in_sizes, int n_in,
                              void* d_out, int out_size, void* d_ws, size_t ws_size,
                              hipStream_t stream) {
    const float* emb = (const float*)d_in[0];
    const int*   ids = (const int*)d_in[1];
    float*       out = (float*)d_out;

    float*  all_sum = (float*)d_ws;
    float*  pos_sum = all_sum + B_SZ;
    ushort* nbf     = (ushort*)((char*)d_ws + 65536);   // 8192*256 bf16 = 4 MB

    norm_kernel<<<B_SZ / 4, 256, 0, stream>>>(emb, nbf, all_sum);
    const int ntiles = (B_SZ / 128) * (B_SZ / 128 + 1) / 2;   // 2080
    sim_kernel<<<ntiles, 512, 0, stream>>>(nbf, ids, all_sum, pos_sum);
    loss_kernel<<<1, 256, 0, stream>>>(all_sum, pos_sum, out);
}

// Round 8
// 288.432 us; speedup vs baseline: 1.0096x; 1.0096x over previous
//
#include <hip/hip_runtime.h>
#include <hip/hip_bf16.h>

#define B_SZ 8192
#define D_SZ 256
// rows pre-scaled by sqrt(log2(e)/T): exp2(acc) == exp(sim/T)
#define PRESCALE 4.539816004686735f

typedef __attribute__((ext_vector_type(4))) float f32x4;
typedef __attribute__((ext_vector_type(8))) short s16x8;

// ---- async global->LDS, 16B per lane (wave-uniform LDS base + lane*16) ----
__device__ __forceinline__ void async_copy16(const void* g, void* l) {
    __builtin_amdgcn_global_load_lds(
        (const __attribute__((address_space(1))) unsigned int*)g,
        (__attribute__((address_space(3))) unsigned int*)l,
        16, 0, 0);
}

// ---------------- L2-normalize rows, scale, cast to bf16 (+ zero sums) -----
__global__ __launch_bounds__(256) void norm_kernel(const float* __restrict__ emb,
                                                   ushort* __restrict__ nbf,
                                                   float* __restrict__ sums) {
    if (blockIdx.x < 64) sums[blockIdx.x * 256 + threadIdx.x] = 0.0f;

    int wave = threadIdx.x >> 6, lane = threadIdx.x & 63;
    int row  = blockIdx.x * 4 + wave;
    const float4 v = ((const float4*)(emb + (size_t)row * D_SZ))[lane];
    float ss = v.x * v.x + v.y * v.y + v.z * v.z + v.w * v.w;
    #pragma unroll
    for (int m = 1; m < 64; m <<= 1) ss += __shfl_xor(ss, m, 64);
    float s = PRESCALE / fmaxf(sqrtf(ss), 1e-12f);
    __hip_bfloat16 b0 = __float2bfloat16(v.x * s);
    __hip_bfloat16 b1 = __float2bfloat16(v.y * s);
    __hip_bfloat16 b2 = __float2bfloat16(v.z * s);
    __hip_bfloat16 b3 = __float2bfloat16(v.w * s);
    ushort4 o;
    o.x = *(ushort*)&b0; o.y = *(ushort*)&b1; o.z = *(ushort*)&b2; o.w = *(ushort*)&b3;
    ((ushort4*)(nbf + (size_t)row * D_SZ))[lane] = o;
}

// ---------------- fused sim tile: upper triangle, LDS-staged matmul --------
// 128x128 tile, 512 threads = 8 waves (2x4 grid: wy rows-64, wx cols-32).
// BK=64, mfma 16x16x32 bf16, XOR-swizzled LDS chunks (banks verified 0-conflict r7).
// launch_bounds(512,2): reg cap >=128 under either HIP semantics -> no spill
// (r6/r7 lesson: (512,4)/(512,6) capped at 64/42 regs and spilled to scratch).
__global__ __launch_bounds__(512, 2) void sim_kernel(const ushort* __restrict__ N,
                                                     const int* __restrict__ ids,
                                                     float* __restrict__ all_sum,
                                                     float* __restrict__ pos_sum) {
    __shared__ ushort sA[128 * 64];   // reused: rowAll partials [128][18] f32
    __shared__ ushort sB[128 * 64];   // reused: rowPos partials [128][18] f32
    __shared__ int   sIdR[128], sIdC[128];

    const int t    = threadIdx.x;
    const int wave = t >> 6, lane = t & 63;
    const int wy   = wave >> 2, wx = wave & 3;

    // decode upper-triangular tile pair: tb = bj*(bj+1)/2 + bi, bi <= bj
    int tb = blockIdx.x;
    int bj = (int)((sqrtf(8.0f * tb + 1.0f) - 1.0f) * 0.5f);
    while ((bj + 1) * (bj + 2) / 2 <= tb) ++bj;
    while (bj * (bj + 1) / 2 > tb) --bj;
    const int bi   = tb - bj * (bj + 1) / 2;
    const int i0   = bi * 128;
    const int j0   = bj * 128;
    const bool diag = (bi == bj);

    if (t < 128)      sIdR[t] = ids[i0 + t];
    else if (t < 256) sIdC[t - 128] = ids[j0 + (t - 128)];
    // (first K-loop barrier orders these before epilogue use)

    f32x4 acc[4][2];
    #pragma unroll
    for (int mi = 0; mi < 4; ++mi)
        #pragma unroll
        for (int ni = 0; ni < 2; ++ni)
            acc[mi][ni] = (f32x4){0.f, 0.f, 0.f, 0.f};

    const int r   = lane >> 3;                      // 0..7 sub-row
    const int c8s = ((lane & 7) ^ r) * 8;           // swizzled source chunk

    for (int kk = 0; kk < 4; ++kk) {
        const int k0 = kk * 64;
        // each wave stages 16 rows of A and 16 rows of B (2 instrs each)
        const ushort* gA = N + (size_t)(i0 + wave * 16) * D_SZ + k0;
        const ushort* gB = N + (size_t)(j0 + wave * 16) * D_SZ + k0;
        #pragma unroll
        for (int q = 0; q < 2; ++q) {
            async_copy16(gA + (size_t)(q * 8 + r) * D_SZ + c8s, &sA[(wave * 16 + q * 8) * 64]);
            async_copy16(gB + (size_t)(q * 8 + r) * D_SZ + c8s, &sB[(wave * 16 + q * 8) * 64]);
        }
        __syncthreads();

        #pragma unroll
        for (int ks = 0; ks < 2; ++ks) {
            const int C = ks * 4 + (lane >> 4);     // k-chunk index 0..7
            const int slot = (C ^ (lane & 7)) * 8;  // un-swizzle
            s16x8 af[4], bf[2];
            #pragma unroll
            for (int mi = 0; mi < 4; ++mi)
                af[mi] = *(const s16x8*)&sA[(wy * 64 + mi * 16 + (lane & 15)) * 64 + slot];
            #pragma unroll
            for (int ni = 0; ni < 2; ++ni)
                bf[ni] = *(const s16x8*)&sB[(wx * 32 + ni * 16 + (lane & 15)) * 64 + slot];
            #pragma unroll
            for (int mi = 0; mi < 4; ++mi)
                #pragma unroll
                for (int ni = 0; ni < 2; ++ni)
                    acc[mi][ni] = __builtin_amdgcn_mfma_f32_16x16x32_bf16(
                        af[mi], bf[ni], acc[mi][ni], 0, 0, 0);
        }
        __syncthreads();   // also guarantees sA/sB free for epilogue reuse
    }

    // ---- epilogue.  C/D map: col=lane&15, row=(lane>>4)*4+reg ----
    float* rowAllPart = (float*)sA;   // [128][18]; stride 18 -> <=2-way banks
    float* rowPosPart = (float*)sB;

    for (int z = t; z < 128 * 18; z += 512) {
        rowAllPart[z] = 0.0f;
        rowPosPart[z] = 0.0f;
    }
    __syncthreads();

    const int myc = lane & 15;
    float cAll[2] = {0.f, 0.f};
    float cPos[2] = {0.f, 0.f};

    #pragma unroll
    for (int mi = 0; mi < 4; ++mi) {
        float rAll[4] = {0.f, 0.f, 0.f, 0.f};
        float rPos[4] = {0.f, 0.f, 0.f, 0.f};
        const int rbase = wy * 64 + mi * 16 + (lane >> 4) * 4;
        const int4 idr  = *(const int4*)&sIdR[rbase];
        #pragma unroll
        for (int ni = 0; ni < 2; ++ni) {
            const int cloc = wx * 32 + ni * 16 + myc;
            const int idc  = sIdC[cloc];
            #pragma unroll
            for (int rg = 0; rg < 4; ++rg) {
                const int lr = rbase + rg;
                float e = __builtin_amdgcn_exp2f(acc[mi][ni][rg]);
                if (diag && lr == cloc) e = 0.0f;        // diagonal element
                rAll[rg] += e; cAll[ni] += e;
                const int idrv = (rg == 0) ? idr.x : (rg == 1) ? idr.y
                               : (rg == 2) ? idr.z : idr.w;
                if (idrv == idc) { rPos[rg] += e; cPos[ni] += e; }
            }
        }
        #pragma unroll
        for (int rg = 0; rg < 4; ++rg) {
            atomicAdd(&rowAllPart[(rbase + rg) * 18 + myc], rAll[rg]);
            atomicAdd(&rowPosPart[(rbase + rg) * 18 + myc], rPos[rg]);
        }
    }

    // column sums -> rows j (off-diagonal tiles only; symmetry)
    if (!diag) {
        #pragma unroll
        for (int ni = 0; ni < 2; ++ni) {
            cAll[ni] += __shfl_xor(cAll[ni], 16, 64);
            cAll[ni] += __shfl_xor(cAll[ni], 32, 64);
            cPos[ni] += __shfl_xor(cPos[ni], 16, 64);
            cPos[ni] += __shfl_xor(cPos[ni], 32, 64);
        }
        if (lane < 16) {
            #pragma unroll
            for (int ni = 0; ni < 2; ++ni) {
                const int gc = j0 + wx * 32 + ni * 16 + lane;
                atomicAdd(&all_sum[gc], cAll[ni]);
                atomicAdd(&pos_sum[gc], cPos[ni]);
            }
        }
    }

    __syncthreads();
    // row partial reduce: thread t<256 -> (row = t&127, array = t>>7)
    if (t < 256) {
        const int row = t & 127;
        const float* src = (t >= 128) ? rowPosPart : rowAllPart;
        float s = 0.0f;
        #pragma unroll
        for (int k = 0; k < 16; ++k) s += src[row * 18 + k];
        float* dst = (t >= 128) ? pos_sum : all_sum;
        atomicAdd(&dst[i0 + row], s);
    }
}

// ---------------- final scalar reduce ----------------
__global__ __launch_bounds__(256) void loss_kernel(const float* __restrict__ all_sum,
                                                   const float* __restrict__ pos_sum,
                                                   float* __restrict__ out) {
    float loss = 0.0f, cnt = 0.0f;
    for (int i = threadIdx.x; i < B_SZ; i += 256) {
        float p = pos_sum[i], a = all_sum[i];
        if (p > 0.0f) { loss += logf(a) - logf(p); cnt += 1.0f; }
    }
    #pragma unroll
    for (int m = 1; m < 64; m <<= 1) {
        loss += __shfl_xor(loss, m, 64);
        cnt  += __shfl_xor(cnt, m, 64);
    }
    __shared__ float sl[4], sc[4];
    int wave = threadIdx.x >> 6, lane = threadIdx.x & 63;
    if (lane == 0) { sl[wave] = loss; sc[wave] = cnt; }
    __syncthreads();
    if (threadIdx.x == 0) {
        float L = sl[0] + sl[1] + sl[2] + sl[3];
        float C = sc[0] + sc[1] + sc[2] + sc[3];
        out[0] = L / fmaxf(C, 1.0f);
    }
}

extern "C" void kernel_launch(void* const* d_in, const int* in_sizes, int n_in,
                              void* d_out, int out_size, void* d_ws, size_t ws_size,
                              hipStream_t stream) {
    const float* emb = (const float*)d_in[0];
    const int*   ids = (const int*)d_in[1];
    float*       out = (float*)d_out;

    float*  all_sum = (float*)d_ws;
    float*  pos_sum = all_sum + B_SZ;
    ushort* nbf     = (ushort*)((char*)d_ws + 65536);   // 8192*256 bf16 = 4 MB

    norm_kernel<<<B_SZ / 4, 256, 0, stream>>>(emb, nbf, all_sum);
    const int ntiles = (B_SZ / 128) * (B_SZ / 128 + 1) / 2;   // 2080
    sim_kernel<<<ntiles, 512, 0, stream>>>(nbf, ids, all_sum, pos_sum);
    loss_kernel<<<1, 256, 0, stream>>>(all_sum, pos_sum, out);
}

// Round 9
// 122.591 us; speedup vs baseline: 2.3754x; 2.3528x over previous
//
#include <hip/hip_runtime.h>
#include <hip/hip_bf16.h>

#define B_SZ 8192
#define D_SZ 256
// rows pre-scaled by sqrt(log2(e)/T): exp2(acc) == exp(sim/T)
#define PRESCALE 4.539816004686735f

typedef __attribute__((ext_vector_type(4))) float f32x4;
typedef __attribute__((ext_vector_type(8))) short s16x8;

// ---- async global->LDS, 16B per lane (wave-uniform LDS base + lane*16) ----
__device__ __forceinline__ void async_copy16(const void* g, void* l) {
    __builtin_amdgcn_global_load_lds(
        (const __attribute__((address_space(1))) unsigned int*)g,
        (__attribute__((address_space(3))) unsigned int*)l,
        16, 0, 0);
}

// ---------------- L2-normalize rows, scale, cast to bf16 (+ zero sums) -----
__global__ __launch_bounds__(256) void norm_kernel(const float* __restrict__ emb,
                                                   ushort* __restrict__ nbf,
                                                   float* __restrict__ sums) {
    if (blockIdx.x < 64) sums[blockIdx.x * 256 + threadIdx.x] = 0.0f;

    int wave = threadIdx.x >> 6, lane = threadIdx.x & 63;
    int row  = blockIdx.x * 4 + wave;
    const float4 v = ((const float4*)(emb + (size_t)row * D_SZ))[lane];
    float ss = v.x * v.x + v.y * v.y + v.z * v.z + v.w * v.w;
    #pragma unroll
    for (int m = 1; m < 64; m <<= 1) ss += __shfl_xor(ss, m, 64);
    float s = PRESCALE / fmaxf(sqrtf(ss), 1e-12f);
    __hip_bfloat16 b0 = __float2bfloat16(v.x * s);
    __hip_bfloat16 b1 = __float2bfloat16(v.y * s);
    __hip_bfloat16 b2 = __float2bfloat16(v.z * s);
    __hip_bfloat16 b3 = __float2bfloat16(v.w * s);
    ushort4 o;
    o.x = *(ushort*)&b0; o.y = *(ushort*)&b1; o.z = *(ushort*)&b2; o.w = *(ushort*)&b3;
    ((ushort4*)(nbf + (size_t)row * D_SZ))[lane] = o;
}

// ---------------- fused sim tile: upper triangle, LDS-staged matmul --------
// 128x128 tile, 256 threads = 4 waves (2x2), BK=64, mfma 16x16x32 bf16.
// XOR-swizzled staging (slot c of row r holds chunk c^(r&7)) -> conflict-free.
// LDS = sA+sB = 32768 B exactly -> 5 blocks/CU. ids read from global (L1-hot).
// Epilogue partials [128][32] include wx in the column -> each slot written
// exactly ONCE (fixes r5's wx-overwrite race; no atomics, no zero-init).
// NOTE: no 2nd __launch_bounds__ arg — r6/r7/r8 showed it poisons codegen.
__global__ __launch_bounds__(256) void sim_kernel(const ushort* __restrict__ N,
                                                  const int* __restrict__ ids,
                                                  float* __restrict__ all_sum,
                                                  float* __restrict__ pos_sum) {
    __shared__ ushort sA[128 * 64];   // staging; reused as rowAll partials [128][32] f32
    __shared__ ushort sB[128 * 64];   // staging; reused as rowPos partials [128][32] f32

    const int t    = threadIdx.x;
    const int wave = t >> 6, lane = t & 63;
    const int wy   = wave >> 1, wx = wave & 1;

    // decode upper-triangular tile pair: tb = bj*(bj+1)/2 + bi, bi <= bj
    int tb = blockIdx.x;
    int bj = (int)((sqrtf(8.0f * tb + 1.0f) - 1.0f) * 0.5f);
    while ((bj + 1) * (bj + 2) / 2 <= tb) ++bj;
    while (bj * (bj + 1) / 2 > tb) --bj;
    const int bi   = tb - bj * (bj + 1) / 2;
    const int i0   = bi * 128;
    const int j0   = bj * 128;
    const bool diag = (bi == bj);

    f32x4 acc[4][4];
    #pragma unroll
    for (int mi = 0; mi < 4; ++mi)
        #pragma unroll
        for (int ni = 0; ni < 4; ++ni)
            acc[mi][ni] = (f32x4){0.f, 0.f, 0.f, 0.f};

    const int r   = lane >> 3;                      // 0..7 sub-row
    const int c8s = ((lane & 7) ^ r) * 8;           // swizzled source chunk

    for (int kk = 0; kk < 4; ++kk) {
        const int k0 = kk * 64;
        const ushort* gA = N + (size_t)(i0 + wave * 32) * D_SZ + k0;
        const ushort* gB = N + (size_t)(j0 + wave * 32) * D_SZ + k0;
        #pragma unroll
        for (int q = 0; q < 4; ++q) {
            async_copy16(gA + (size_t)(q * 8 + r) * D_SZ + c8s, &sA[(wave * 32 + q * 8) * 64]);
            async_copy16(gB + (size_t)(q * 8 + r) * D_SZ + c8s, &sB[(wave * 32 + q * 8) * 64]);
        }
        __syncthreads();

        #pragma unroll
        for (int ks = 0; ks < 2; ++ks) {
            const int C = ks * 4 + (lane >> 4);     // k-chunk index 0..7
            const int slot = (C ^ (lane & 7)) * 8;  // un-swizzle
            s16x8 af[4], bf[4];
            #pragma unroll
            for (int mi = 0; mi < 4; ++mi)
                af[mi] = *(const s16x8*)&sA[(wy * 64 + mi * 16 + (lane & 15)) * 64 + slot];
            #pragma unroll
            for (int ni = 0; ni < 4; ++ni)
                bf[ni] = *(const s16x8*)&sB[(wx * 64 + ni * 16 + (lane & 15)) * 64 + slot];
            #pragma unroll
            for (int mi = 0; mi < 4; ++mi)
                #pragma unroll
                for (int ni = 0; ni < 4; ++ni)
                    acc[mi][ni] = __builtin_amdgcn_mfma_f32_16x16x32_bf16(
                        af[mi], bf[ni], acc[mi][ni], 0, 0, 0);
        }
        __syncthreads();   // also guarantees sA/sB free for epilogue reuse
    }

    // ---- epilogue.  C/D map: col=lane&15, row=(lane>>4)*4+reg ----
    float* rowAllPart = (float*)sA;   // [128][32], col = wx*16+myc (unique writer)
    float* rowPosPart = (float*)sB;
    const int myc = lane & 15;

    // column ids for this wave's 64 columns (global, L1-hot, coalesced)
    int idc[4];
    #pragma unroll
    for (int ni = 0; ni < 4; ++ni)
        idc[ni] = ids[j0 + wx * 64 + ni * 16 + myc];

    float cAll[4] = {0.f, 0.f, 0.f, 0.f};
    float cPos[4] = {0.f, 0.f, 0.f, 0.f};

    #pragma unroll
    for (int mi = 0; mi < 4; ++mi) {
        float rAll[4] = {0.f, 0.f, 0.f, 0.f};
        float rPos[4] = {0.f, 0.f, 0.f, 0.f};
        const int rbase = wy * 64 + mi * 16 + (lane >> 4) * 4;
        const int4 idr  = *(const int4*)&ids[i0 + rbase];   // 16B aligned
        #pragma unroll
        for (int ni = 0; ni < 4; ++ni) {
            const int cloc = wx * 64 + ni * 16 + myc;
            #pragma unroll
            for (int rg = 0; rg < 4; ++rg) {
                const int lr = rbase + rg;
                float e = __builtin_amdgcn_exp2f(acc[mi][ni][rg]);
                if (diag && lr == cloc) e = 0.0f;        // diagonal element
                rAll[rg] += e; cAll[ni] += e;
                const int idrv = (rg == 0) ? idr.x : (rg == 1) ? idr.y
                               : (rg == 2) ? idr.z : idr.w;
                if (idrv == idc[ni]) { rPos[rg] += e; cPos[ni] += e; }
            }
        }
        #pragma unroll
        for (int rg = 0; rg < 4; ++rg) {
            rowAllPart[(rbase + rg) * 32 + wx * 16 + myc] = rAll[rg];
            rowPosPart[(rbase + rg) * 32 + wx * 16 + myc] = rPos[rg];
        }
    }

    // column sums -> rows j (off-diagonal tiles only; symmetry)
    if (!diag) {
        #pragma unroll
        for (int ni = 0; ni < 4; ++ni) {
            cAll[ni] += __shfl_xor(cAll[ni], 16, 64);
            cAll[ni] += __shfl_xor(cAll[ni], 32, 64);
            cPos[ni] += __shfl_xor(cPos[ni], 16, 64);
            cPos[ni] += __shfl_xor(cPos[ni], 32, 64);
        }
        if (lane < 16) {
            #pragma unroll
            for (int ni = 0; ni < 4; ++ni) {
                const int gc = j0 + wx * 64 + ni * 16 + lane;
                atomicAdd(&all_sum[gc], cAll[ni]);
                atomicAdd(&pos_sum[gc], cPos[ni]);
            }
        }
    }

    __syncthreads();
    // row partial reduce: thread t -> (row = t&127, array = t>>7).
    // start chunk rotated by row&7 -> <=2-way LDS banks.
    {
        const int row = t & 127;
        const float* src = (t >= 128) ? rowPosPart : rowAllPart;
        float s = 0.0f;
        #pragma unroll
        for (int k8 = 0; k8 < 8; ++k8) {
            const int chunk = (k8 + (row & 7)) & 7;
            const float4 v = *(const float4*)&src[row * 32 + chunk * 4];
            s += v.x + v.y + v.z + v.w;
        }
        float* dst = (t >= 128) ? pos_sum : all_sum;
        atomicAdd(&dst[i0 + row], s);
    }
}

// ---------------- final scalar reduce ----------------
__global__ __launch_bounds__(256) void loss_kernel(const float* __restrict__ all_sum,
                                                   const float* __restrict__ pos_sum,
                                                   float* __restrict__ out) {
    float loss = 0.0f, cnt = 0.0f;
    for (int i = threadIdx.x; i < B_SZ; i += 256) {
        float p = pos_sum[i], a = all_sum[i];
        if (p > 0.0f) { loss += logf(a) - logf(p); cnt += 1.0f; }
    }
    #pragma unroll
    for (int m = 1; m < 64; m <<= 1) {
        loss += __shfl_xor(loss, m, 64);
        cnt  += __shfl_xor(cnt, m, 64);
    }
    __shared__ float sl[4], sc[4];
    int wave = threadIdx.x >> 6, lane = threadIdx.x & 63;
    if (lane == 0) { sl[wave] = loss; sc[wave] = cnt; }
    __syncthreads();
    if (threadIdx.x == 0) {
        float L = sl[0] + sl[1] + sl[2] + sl[3];
        float C = sc[0] + sc[1] + sc[2] + sc[3];
        out[0] = L / fmaxf(C, 1.0f);
    }
}

extern "C" void kernel_launch(void* const* d_in, const int* in_sizes, int n_in,
                              void* d_out, int out_size, void* d_ws, size_t ws_size,
                              hipStream_t stream) {
    const float* emb = (const float*)d_in[0];
    const int*   ids = (const int*)d_in[1];
    float*       out = (float*)d_out;

    float*  all_sum = (float*)d_ws;
    float*  pos_sum = all_sum + B_SZ;
    ushort* nbf     = (ushort*)((char*)d_ws + 65536);   // 8192*256 bf16 = 4 MB

    norm_kernel<<<B_SZ / 4, 256, 0, stream>>>(emb, nbf, all_sum);
    const int ntiles = (B_SZ / 128) * (B_SZ / 128 + 1) / 2;   // 2080
    sim_kernel<<<ntiles, 256, 0, stream>>>(nbf, ids, all_sum, pos_sum);
    loss_kernel<<<1, 256, 0, stream>>>(all_sum, pos_sum, out);
}